// Round 1
// baseline (230.879 us; speedup 1.0000x reference)
//
#include <hip/hip_runtime.h>
#include <cstdint>
#include <cmath>

#define B_ 8
#define S_ 1024
#define D_ 768
#define H_ 12
#define HD_ 64

typedef __bf16 bf16;
typedef __attribute__((ext_vector_type(8))) __bf16 bf16x8;
typedef __attribute__((ext_vector_type(4))) float floatx4;

typedef const __attribute__((address_space(1))) unsigned int* gas_ptr;
typedef __attribute__((address_space(3))) unsigned int* las_ptr;

// async global->LDS, 16B per lane. LDS dest must be wave-uniform base + lane*16.
__device__ __forceinline__ void async_ld16(const void* g, void* l) {
    gas_ptr gp = (gas_ptr)(uintptr_t)g;
    las_ptr lp = (las_ptr)(unsigned)(uintptr_t)l;
    __builtin_amdgcn_global_load_lds(gp, lp, 16, 0, 0);
}

// ---------------- tiled transpose-convert body: in[K][N] f32 -> out[N][K] bf16
__device__ __forceinline__ void transpose_dev(const float* __restrict__ in,
                                              bf16* __restrict__ out,
                                              int N, int K, int n0, int k0,
                                              bf16 (*tile)[66], int tid) {
#pragma unroll
    for (int r = 0; r < 4; r++) {
        int idx = r * 256 + tid;
        int row = idx >> 4;
        int c0  = (idx & 15) * 4;
        float4 v = *(const float4*)(in + (size_t)(k0 + row) * N + n0 + c0);
        tile[c0 + 0][row] = (bf16)v.x;
        tile[c0 + 1][row] = (bf16)v.y;
        tile[c0 + 2][row] = (bf16)v.z;
        tile[c0 + 3][row] = (bf16)v.w;
    }
    __syncthreads();
#pragma unroll
    for (int r = 0; r < 2; r++) {
        int idx = r * 256 + tid;
        int orow = idx >> 3;
        int kk   = (idx & 7) * 8;
        union { bf16x8 v; bf16 e[8]; } u;
#pragma unroll
        for (int j = 0; j < 8; j++) u.e[j] = tile[orow][kk + j];
        *(bf16x8*)(out + (size_t)(n0 + orow) * K + k0 + kk) = u.v;
    }
}

// ---------------- fused prep: x f32->bf16 (blocks 0..6143), w_qkv^T (6144..6575),
// w_proj^T (6576..6719)
__global__ __launch_bounds__(256) void prep_all(
    const float* __restrict__ x, const float* __restrict__ w_qkv,
    const float* __restrict__ w_proj,
    bf16* __restrict__ xb, bf16* __restrict__ wqkvt, bf16* __restrict__ wprojt)
{
    __shared__ bf16 tile[64][66];
    const int blk = blockIdx.x, tid = threadIdx.x;
    if (blk < 6144) {
        int i = (blk * 256 + tid) * 4;
        float4 v = *(const float4*)(x + i);
        xb[i]     = (bf16)v.x;
        xb[i + 1] = (bf16)v.y;
        xb[i + 2] = (bf16)v.z;
        xb[i + 3] = (bf16)v.w;
    } else if (blk < 6576) {
        int t = blk - 6144;
        transpose_dev(w_qkv, wqkvt, 2304, 768, (t % 36) * 64, (t / 36) * 64, tile, tid);
    } else {
        int t = blk - 6576;
        transpose_dev(w_proj, wprojt, 768, 768, (t % 12) * 64, (t / 12) * 64, tile, tid);
    }
}

// ---------------- transpose V: vbuf[b][s][768] (head dims in d'-order) -> vt[b][h][d][1024],
// keys PERMUTED for the PV B-operand: within each 32-key group, permuted position kp
// (g=kp>>3, j=kp&7) holds true key  j<4 ? 4g+j : 16+4g+(j-4).
// vbuf memory position p within a head holds true dim dt = (p>>2) + 16*(p&3).
__global__ void transpose_v(const bf16* __restrict__ vbuf, bf16* __restrict__ vt) {
    __shared__ bf16 tile[64][66];     // [true d][key true order]
    const int tid = threadIdx.x;
    const int kt = blockIdx.x, h = blockIdx.y, b = blockIdx.z;
    const bf16* src = vbuf + ((size_t)b * S_ + (size_t)kt * 64) * D_ + h * 64;
#pragma unroll
    for (int r = 0; r < 2; r++) {
        int idx = r * 256 + tid;
        int kr = idx >> 3;
        int d0 = (idx & 7) * 8;
        bf16x8 v = *(const bf16x8*)(src + (size_t)kr * D_ + d0);
#pragma unroll
        for (int j = 0; j < 8; j++) {
            int p  = d0 + j;
            int dt = (p >> 2) + 16 * (p & 3);   // undo d'-permutation
            tile[dt][kr] = v[j];
        }
    }
    __syncthreads();
    bf16* dst = vt + ((size_t)(b * H_ + h) * 64) * 1024 + kt * 64;
#pragma unroll
    for (int r = 0; r < 2; r++) {
        int idx = r * 256 + tid;
        int dr = idx >> 3;
        int k0 = (idx & 7) * 8;
        union { bf16x8 v; bf16 e[8]; } u;
#pragma unroll
        for (int j = 0; j < 8; j++) {
            int kp  = k0 + j;
            int grp = kp & 32;
            int w32 = kp & 31;
            int gg  = w32 >> 3;
            int jj  = w32 & 7;
            int tk  = grp + ((jj < 4) ? (4 * gg + jj) : (16 + 4 * gg + jj - 4));
            u.e[j] = tile[dr][tk];
        }
        *(bf16x8*)(dst + (size_t)dr * 1024 + k0) = u.v;
    }
}

// ---------------- QKV GEMM: [8192][768] x [2304][768]^T + bias -> qpack/kpack/vbuf
// qpack/kpack: [b][h][s][64] with head dims in d'-order, d' = 4*(col&15) + colsub
// (Q scaled by 0.125). vbuf: [b*s][768], heads in d'-order. Wave covers exactly one
// head (64 cols) -> wave-uniform branch, b64 packed stores.
__global__ __launch_bounds__(256, 2) void gemm_qkv(
    const bf16* __restrict__ A, const bf16* __restrict__ Bt,
    const float* __restrict__ bias,
    bf16* __restrict__ qpack, bf16* __restrict__ kpack, bf16* __restrict__ vbuf)
{
    __shared__ __align__(16) bf16 As[128 * 32];
    __shared__ __align__(16) bf16 Bs[128 * 32];
    const int N = 2304, K = 768;

    const int tid  = threadIdx.x;
    const int lane = tid & 63;
    const int w    = tid >> 6;
    const int wm   = (w >> 1) * 64;
    const int wn   = (w & 1) * 64;
    const long m0  = (long)blockIdx.y * 128;
    const long n0  = (long)blockIdx.x * 128;
    const int c    = lane & 15;
    const int g    = lane >> 4;

    const floatx4 fzero = {0.f, 0.f, 0.f, 0.f};
    floatx4 acc[4][4];
#pragma unroll
    for (int i = 0; i < 4; i++)
#pragma unroll
        for (int j = 0; j < 4; j++) acc[i][j] = fzero;

    for (int k0 = 0; k0 < K; k0 += 32) {
        __syncthreads();
#pragma unroll
        for (int r = 0; r < 2; r++) {
            const int idx = r * 256 + tid;
            const int row = idx >> 2;
            const int kk  = (idx & 3) * 8;
            async_ld16(A  + (m0 + row) * (long)K + k0 + kk, (char*)As + idx * 16);
            async_ld16(Bt + (n0 + row) * (long)K + k0 + kk, (char*)Bs + idx * 16);
        }
        __syncthreads();

        bf16x8 af[4], bfr[4];
#pragma unroll
        for (int i = 0; i < 4; i++) {
            af[i]  = *(const bf16x8*)(As + (wm + i * 16 + c) * 32 + g * 8);
            bfr[i] = *(const bf16x8*)(Bs + (wn + i * 16 + c) * 32 + g * 8);
        }
#pragma unroll
        for (int i = 0; i < 4; i++)
#pragma unroll
            for (int j = 0; j < 4; j++)
                acc[i][j] = __builtin_amdgcn_mfma_f32_16x16x32_bf16(af[i], bfr[j], acc[i][j], 0, 0, 0);
    }

    // epilogue: wave-uniform head = (n0+wn)/64; lane c owns d' = 4c..4c+3 (b64 store)
    const int head = (int)((n0 + wn) >> 6);       // 0..35
    const int rm   = wm + g * 4;
    float bv[4];
#pragma unroll
    for (int j = 0; j < 4; j++) bv[j] = bias[(int)n0 + wn + c + 16 * j];
    const int bb    = (int)(m0 >> 10);
    const int sbase = ((int)m0 & 1023) + rm;

    if (head < 24) {
        const float sc = (head < 12) ? 0.125f : 1.0f;
        bf16* dst = ((head < 12) ? qpack : kpack)
                  + (((size_t)((bb * H_ + (head < 12 ? head : head - 12)) * 1024 + sbase)) << 6)
                  + 4 * c;
#pragma unroll
        for (int i = 0; i < 4; i++)
#pragma unroll
            for (int e = 0; e < 4; e++) {
                union { bf16 h4[4]; uint64_t u; } pk;
#pragma unroll
                for (int j = 0; j < 4; j++) pk.h4[j] = (bf16)((acc[i][j][e] + bv[j]) * sc);
                *(uint64_t*)(dst + (size_t)(i * 16 + e) * 64) = pk.u;
            }
    } else {
        bf16* dst = vbuf + ((size_t)(bb * 1024 + sbase)) * 768 + (head - 24) * 64 + 4 * c;
#pragma unroll
        for (int i = 0; i < 4; i++)
#pragma unroll
            for (int e = 0; e < 4; e++) {
                union { bf16 h4[4]; uint64_t u; } pk;
#pragma unroll
                for (int j = 0; j < 4; j++) pk.h4[j] = (bf16)(acc[i][j][e] + bv[j]);
                *(uint64_t*)(dst + (size_t)(i * 16 + e) * 768) = pk.u;
            }
    }
}

// ---------------- generic GEMM (proj): C[M][N] = A[M][K]*Bt[N][K]^T + bias
__global__ __launch_bounds__(256, 2) void gemm_bt(
    const bf16* __restrict__ A, const bf16* __restrict__ Bt,
    const float* __restrict__ bias, float* __restrict__ C,
    int M, int N, int K)
{
    __shared__ __align__(16) bf16 As[128 * 32];
    __shared__ __align__(16) bf16 Bs[128 * 32];

    const int tid  = threadIdx.x;
    const int lane = tid & 63;
    const int w    = tid >> 6;
    const int wm   = (w >> 1) * 64;
    const int wn   = (w & 1) * 64;
    const long m0  = (long)blockIdx.y * 128;
    const long n0  = (long)blockIdx.x * 128;
    const int c    = lane & 15;
    const int g    = lane >> 4;

    const floatx4 fzero = {0.f, 0.f, 0.f, 0.f};
    floatx4 acc[4][4];
#pragma unroll
    for (int i = 0; i < 4; i++)
#pragma unroll
        for (int j = 0; j < 4; j++) acc[i][j] = fzero;

    for (int k0 = 0; k0 < K; k0 += 32) {
        __syncthreads();
#pragma unroll
        for (int r = 0; r < 2; r++) {
            const int idx = r * 256 + tid;
            const int row = idx >> 2;
            const int kk  = (idx & 3) * 8;
            async_ld16(A  + (m0 + row) * (long)K + k0 + kk, (char*)As + idx * 16);
            async_ld16(Bt + (n0 + row) * (long)K + k0 + kk, (char*)Bs + idx * 16);
        }
        __syncthreads();

        bf16x8 af[4], bfr[4];
#pragma unroll
        for (int i = 0; i < 4; i++) {
            af[i]  = *(const bf16x8*)(As + (wm + i * 16 + c) * 32 + g * 8);
            bfr[i] = *(const bf16x8*)(Bs + (wn + i * 16 + c) * 32 + g * 8);
        }
#pragma unroll
        for (int i = 0; i < 4; i++)
#pragma unroll
            for (int j = 0; j < 4; j++)
                acc[i][j] = __builtin_amdgcn_mfma_f32_16x16x32_bf16(af[i], bfr[j], acc[i][j], 0, 0, 0);
    }

    const int cn = wn + c;
    const int rm = wm + g * 4;
#pragma unroll
    for (int j = 0; j < 4; j++) {
        const long gn = n0 + cn + j * 16;
        const float bv = bias[gn];
#pragma unroll
        for (int i = 0; i < 4; i++) {
            const long gm = m0 + rm + i * 16;
#pragma unroll
            for (int e = 0; e < 4; e++)
                C[(gm + e) * (long)N + gn] = acc[i][j][e] + bv;
        }
    }
}

// ---------------- fused attention v4: v3 + double-buffered K/V staging with counted
// vmcnt (T3/T4 minimum 2-phase pipeline). v3 was latency-bound: 6 waves/CU and a
// full vmcnt(0) drain at every __syncthreads -> ~4200 cyc/iter with only ~700 cyc of
// work. Now tile t+1's 4 global_load_lds are issued BEFORE computing tile t; the
// barrier waits vmcnt(4) (current buffer done, next-tile loads stay in flight). A
// lgkmcnt(0)+barrier right after the 8 frag ds_reads frees the buffer, so the 36
// MFMA + exp compute overlaps the outstanding loads. LDS 8KB -> 16KB (3 blk/CU ok).
__global__ __launch_bounds__(128, 3) void attn_fused(
    const bf16* __restrict__ qpack, const bf16* __restrict__ kpack,
    const bf16* __restrict__ vt, bf16* __restrict__ outp)
{
    __shared__ __align__(16) bf16 Ks[2][2048];   // [buf][dc][key][32elem]
    __shared__ __align__(16) bf16 Vs[2][2048];   // [buf][d][32key]

    const int tid  = threadIdx.x;
    const int lane = tid & 63;
    const int w    = tid >> 6;
    const int g    = lane >> 4;
    const int c    = lane & 15;

    const int id = blockIdx.x;
    const int bh = id % 96;           // same-(b,h) blocks share id mod 8 -> same XCD
    const int qt = id / 96;           // 0..7
    const int h  = bh >> 3;
    const int b  = bh & 7;
    const int q0 = qt * 128 + w * 64;
    const bf16* qpb = qpack + ((size_t)(b * H_ + h) * 1024) * 64;
    const bf16* kpb = kpack + ((size_t)(b * H_ + h) * 1024) * 64;
    const bf16* vtb = vt    + ((size_t)(b * H_ + h) * 64) * 1024;

    // stage one 32-key group (4KB K + 4KB V): 4 global_load_lds per thread
    auto stage = [&](int kt_, bf16* Kbuf, bf16* Vbuf) {
        const int kg = kt_ * 32;
#pragma unroll
        for (int r = 0; r < 2; r++) {
            const int i  = r * 128 + tid;
            const int dc = i >> 7, key = (i >> 2) & 31, dch = i & 3;
            async_ld16(kpb + (size_t)(kg + key) * 64 + dc * 32 + dch * 8, (char*)Kbuf + i * 16);
        }
#pragma unroll
        for (int r = 0; r < 2; r++) {
            const int i = r * 128 + tid;
            const int d = i >> 2, kch = i & 3;
            async_ld16(vtb + (size_t)d * 1024 + kg + kch * 8, (char*)Vbuf + i * 16);
        }
    };

    // Q as B-operand: lane holds Q[q = q0+qb*16+c][pos = g*8+j]; loop-invariant
    bf16x8 qf[4][2];
#pragma unroll
    for (int qb = 0; qb < 4; qb++)
#pragma unroll
        for (int dc = 0; dc < 2; dc++)
            qf[qb][dc] = *(const bf16x8*)(qpb + (size_t)(q0 + qb * 16 + c) * 64 + dc * 32 + g * 8);

    union { uint32_t u[4]; bf16x8 v; } onesu;
    onesu.u[0] = onesu.u[1] = onesu.u[2] = onesu.u[3] = 0x3F803F80u;  // bf16 1.0 x8
    const bf16x8 onesf = onesu.v;

    const floatx4 fzero = {0.f, 0.f, 0.f, 0.f};
    floatx4 oacc[4][4];               // [qb][db]: Oᵀ, col=q, row=d (db*16+4g+e)
    floatx4 lacc[4];                  // [qb]: every entry = l[q=c]
#pragma unroll
    for (int qb = 0; qb < 4; qb++) {
        lacc[qb] = fzero;
#pragma unroll
        for (int db = 0; db < 4; db++) oacc[qb][db] = fzero;
    }

    // prologue: stage tile 0 into buf 0
    stage(0, Ks[0], Vs[0]);

#pragma unroll 2
    for (int kt = 0; kt < 32; kt++) {       // 32-key groups, double-buffered
        const int cur = kt & 1;
        bf16* Kc = Ks[cur];
        bf16* Vc = Vs[cur];
        if (kt < 31) {
            stage(kt + 1, Ks[cur ^ 1], Vs[cur ^ 1]);
            // wait for CURRENT buffer's 4 loads only; next tile's 4 stay in flight
            asm volatile("s_waitcnt vmcnt(4)\n\ts_barrier" ::: "memory");
        } else {
            asm volatile("s_waitcnt vmcnt(0)\n\ts_barrier" ::: "memory");
        }

        // K as A-operand: lane holds K[key = kb*16+c][pos = dc*32+g*8+j]
        bf16x8 kf[2][2];
#pragma unroll
        for (int kb = 0; kb < 2; kb++)
#pragma unroll
            for (int dc = 0; dc < 2; dc++)
                kf[kb][dc] = *(const bf16x8*)(Kc + (dc * 32 + kb * 16 + c) * 32 + g * 8);

        // Vᵀ as A-operand: lane holds Vᵀ[d = db*16+c][key' = g*8+j]
        bf16x8 vf[4];
#pragma unroll
        for (int db = 0; db < 4; db++)
            vf[db] = *(const bf16x8*)(Vc + (db * 16 + c) * 32 + g * 8);

        // frags in registers -> current buffer is free for next iter's staging
        asm volatile("s_waitcnt lgkmcnt(0)\n\ts_barrier" ::: "memory");

#pragma unroll
        for (int qb = 0; qb < 4; qb++) {
            // Sᵀ for 32 keys x 16 q
            floatx4 s0 = fzero, s1 = fzero;
#pragma unroll
            for (int dc = 0; dc < 2; dc++) {
                s0 = __builtin_amdgcn_mfma_f32_16x16x32_bf16(kf[0][dc], qf[qb][dc], s0, 0, 0, 0);
                s1 = __builtin_amdgcn_mfma_f32_16x16x32_bf16(kf[1][dc], qf[qb][dc], s1, 0, 0, 0);
            }
            // P = exp(Sᵀ): lane's 8 values are exactly the PV B-operand slots
            union { bf16 e[8]; bf16x8 v; } pa;
#pragma unroll
            for (int e4 = 0; e4 < 4; e4++) {
                pa.e[e4]     = (bf16)__expf(s0[e4]);
                pa.e[e4 + 4] = (bf16)__expf(s1[e4]);
            }
            // Oᵀ += Vᵀ·Pᵀ ; l += 1·Pᵀ
            lacc[qb] = __builtin_amdgcn_mfma_f32_16x16x32_bf16(onesf, pa.v, lacc[qb], 0, 0, 0);
#pragma unroll
            for (int db = 0; db < 4; db++)
                oacc[qb][db] = __builtin_amdgcn_mfma_f32_16x16x32_bf16(vf[db], pa.v, oacc[qb][db], 0, 0, 0);
        }
    }

    // epilogue: lane holds q = q0+qb*16+c, d = db*16+4g+e; pack e-pairs -> b32 stores
#pragma unroll
    for (int qb = 0; qb < 4; qb++) {
        const float linv = 1.0f / lacc[qb][0];
        bf16* orow = outp + ((size_t)b * S_ + q0 + qb * 16 + c) * D_ + h * 64;
#pragma unroll
        for (int db = 0; db < 4; db++)
#pragma unroll
            for (int f = 0; f < 2; f++) {
                union { bf16 hh[2]; uint32_t u; } pk_;
                pk_.hh[0] = (bf16)(oacc[qb][db][2 * f]     * linv);
                pk_.hh[1] = (bf16)(oacc[qb][db][2 * f + 1] * linv);
                *(uint32_t*)(orow + db * 16 + 4 * g + 2 * f) = pk_.u;
            }
    }
}

extern "C" void kernel_launch(void* const* d_in, const int* in_sizes, int n_in,
                              void* d_out, int out_size, void* d_ws, size_t ws_size,
                              hipStream_t stream) {
    const float* x      = (const float*)d_in[0];
    const float* w_qkv  = (const float*)d_in[1];
    const float* b_qkv  = (const float*)d_in[2];
    const float* w_proj = (const float*)d_in[3];
    const float* b_proj = (const float*)d_in[4];
    float* out = (float*)d_out;

    bf16* xb     = (bf16*)d_ws;                       // [8192][768]
    bf16* wqkvt  = xb     + (size_t)8192 * 768;       // [2304][768]
    bf16* wprojt = wqkvt  + (size_t)2304 * 768;       // [768][768]
    bf16* qpack  = wprojt + (size_t)768 * 768;        // [8][12][1024][64] d'-order
    bf16* kpack  = qpack  + (size_t)96 * 1024 * 64;   // [8][12][1024][64] d'-order
    bf16* vbuf   = kpack  + (size_t)96 * 1024 * 64;   // [8192][768] d'-order heads
    bf16* vt     = vbuf   + (size_t)8192 * 768;       // [8][12][64][1024] true-d, perm keys
    bf16* attnb  = xb;                                // alias (xb dead after QKV GEMM)

    prep_all<<<6720, 256, 0, stream>>>(x, w_qkv, w_proj, xb, wqkvt, wprojt);
    gemm_qkv<<<dim3(18, 64), 256, 0, stream>>>(xb, wqkvt, b_qkv, qpack, kpack, vbuf);
    transpose_v<<<dim3(16, 12, 8), 256, 0, stream>>>(vbuf, vt);
    attn_fused<<<768, 128, 0, stream>>>(qpack, kpack, vt, attnb);
    gemm_bt<<<dim3(6, 64), 256, 0, stream>>>(attnb, wprojt, b_proj, out, 8192, 768, 768);
}

// Round 2
// 200.132 us; speedup vs baseline: 1.1536x; 1.1536x over previous
//
#include <hip/hip_runtime.h>
#include <cstdint>
#include <cmath>

#define B_ 8
#define S_ 1024
#define D_ 768
#define H_ 12
#define HD_ 64

typedef __bf16 bf16;
typedef __attribute__((ext_vector_type(8))) __bf16 bf16x8;
typedef __attribute__((ext_vector_type(4))) float floatx4;

typedef const __attribute__((address_space(1))) unsigned int* gas_ptr;
typedef __attribute__((address_space(3))) unsigned int* las_ptr;

// async global->LDS, 16B per lane. LDS dest must be wave-uniform base + lane*16.
__device__ __forceinline__ void async_ld16(const void* g, void* l) {
    gas_ptr gp = (gas_ptr)(uintptr_t)g;
    las_ptr lp = (las_ptr)(unsigned)(uintptr_t)l;
    __builtin_amdgcn_global_load_lds(gp, lp, 16, 0, 0);
}

// ---------------- tiled transpose-convert body: in[K][N] f32 -> out[N][K] bf16
__device__ __forceinline__ void transpose_dev(const float* __restrict__ in,
                                              bf16* __restrict__ out,
                                              int N, int K, int n0, int k0,
                                              bf16 (*tile)[66], int tid) {
#pragma unroll
    for (int r = 0; r < 4; r++) {
        int idx = r * 256 + tid;
        int row = idx >> 4;
        int c0  = (idx & 15) * 4;
        float4 v = *(const float4*)(in + (size_t)(k0 + row) * N + n0 + c0);
        tile[c0 + 0][row] = (bf16)v.x;
        tile[c0 + 1][row] = (bf16)v.y;
        tile[c0 + 2][row] = (bf16)v.z;
        tile[c0 + 3][row] = (bf16)v.w;
    }
    __syncthreads();
#pragma unroll
    for (int r = 0; r < 2; r++) {
        int idx = r * 256 + tid;
        int orow = idx >> 3;
        int kk   = (idx & 7) * 8;
        union { bf16x8 v; bf16 e[8]; } u;
#pragma unroll
        for (int j = 0; j < 8; j++) u.e[j] = tile[orow][kk + j];
        *(bf16x8*)(out + (size_t)(n0 + orow) * K + k0 + kk) = u.v;
    }
}

// ---------------- fused prep: x f32->bf16 (blocks 0..6143), w_qkv^T (6144..6575),
// w_proj^T (6576..6719)
__global__ __launch_bounds__(256) void prep_all(
    const float* __restrict__ x, const float* __restrict__ w_qkv,
    const float* __restrict__ w_proj,
    bf16* __restrict__ xb, bf16* __restrict__ wqkvt, bf16* __restrict__ wprojt)
{
    __shared__ bf16 tile[64][66];
    const int blk = blockIdx.x, tid = threadIdx.x;
    if (blk < 6144) {
        int i = (blk * 256 + tid) * 4;
        float4 v = *(const float4*)(x + i);
        xb[i]     = (bf16)v.x;
        xb[i + 1] = (bf16)v.y;
        xb[i + 2] = (bf16)v.z;
        xb[i + 3] = (bf16)v.w;
    } else if (blk < 6576) {
        int t = blk - 6144;
        transpose_dev(w_qkv, wqkvt, 2304, 768, (t % 36) * 64, (t / 36) * 64, tile, tid);
    } else {
        int t = blk - 6576;
        transpose_dev(w_proj, wprojt, 768, 768, (t % 12) * 64, (t / 12) * 64, tile, tid);
    }
}

// ---------------- transpose V: vbuf[b][s][768] (head dims in d'-order) -> vt[b][h][d][1024],
// keys PERMUTED for the PV B-operand: within each 32-key group, permuted position kp
// (g=kp>>3, j=kp&7) holds true key  j<4 ? 4g+j : 16+4g+(j-4).
// vbuf memory position p within a head holds true dim dt = (p>>2) + 16*(p&3).
__global__ void transpose_v(const bf16* __restrict__ vbuf, bf16* __restrict__ vt) {
    __shared__ bf16 tile[64][66];     // [true d][key true order]
    const int tid = threadIdx.x;
    const int kt = blockIdx.x, h = blockIdx.y, b = blockIdx.z;
    const bf16* src = vbuf + ((size_t)b * S_ + (size_t)kt * 64) * D_ + h * 64;
#pragma unroll
    for (int r = 0; r < 2; r++) {
        int idx = r * 256 + tid;
        int kr = idx >> 3;
        int d0 = (idx & 7) * 8;
        bf16x8 v = *(const bf16x8*)(src + (size_t)kr * D_ + d0);
#pragma unroll
        for (int j = 0; j < 8; j++) {
            int p  = d0 + j;
            int dt = (p >> 2) + 16 * (p & 3);   // undo d'-permutation
            tile[dt][kr] = v[j];
        }
    }
    __syncthreads();
    bf16* dst = vt + ((size_t)(b * H_ + h) * 64) * 1024 + kt * 64;
#pragma unroll
    for (int r = 0; r < 2; r++) {
        int idx = r * 256 + tid;
        int dr = idx >> 3;
        int k0 = (idx & 7) * 8;
        union { bf16x8 v; bf16 e[8]; } u;
#pragma unroll
        for (int j = 0; j < 8; j++) {
            int kp  = k0 + j;
            int grp = kp & 32;
            int w32 = kp & 31;
            int gg  = w32 >> 3;
            int jj  = w32 & 7;
            int tk  = grp + ((jj < 4) ? (4 * gg + jj) : (16 + 4 * gg + jj - 4));
            u.e[j] = tile[dr][tk];
        }
        *(bf16x8*)(dst + (size_t)dr * 1024 + k0) = u.v;
    }
}

// ---------------- QKV GEMM: [8192][768] x [2304][768]^T + bias -> qpack/kpack/vbuf
// qpack/kpack: [b][h][s][64] with head dims in d'-order, d' = 4*(col&15) + colsub
// (Q scaled by 0.125). vbuf: [b*s][768], heads in d'-order. Wave covers exactly one
// head (64 cols) -> wave-uniform branch, b64 packed stores.
__global__ __launch_bounds__(256, 2) void gemm_qkv(
    const bf16* __restrict__ A, const bf16* __restrict__ Bt,
    const float* __restrict__ bias,
    bf16* __restrict__ qpack, bf16* __restrict__ kpack, bf16* __restrict__ vbuf)
{
    __shared__ __align__(16) bf16 As[128 * 32];
    __shared__ __align__(16) bf16 Bs[128 * 32];
    const int N = 2304, K = 768;

    const int tid  = threadIdx.x;
    const int lane = tid & 63;
    const int w    = tid >> 6;
    const int wm   = (w >> 1) * 64;
    const int wn   = (w & 1) * 64;
    const long m0  = (long)blockIdx.y * 128;
    const long n0  = (long)blockIdx.x * 128;
    const int c    = lane & 15;
    const int g    = lane >> 4;

    const floatx4 fzero = {0.f, 0.f, 0.f, 0.f};
    floatx4 acc[4][4];
#pragma unroll
    for (int i = 0; i < 4; i++)
#pragma unroll
        for (int j = 0; j < 4; j++) acc[i][j] = fzero;

    for (int k0 = 0; k0 < K; k0 += 32) {
        __syncthreads();
#pragma unroll
        for (int r = 0; r < 2; r++) {
            const int idx = r * 256 + tid;
            const int row = idx >> 2;
            const int kk  = (idx & 3) * 8;
            async_ld16(A  + (m0 + row) * (long)K + k0 + kk, (char*)As + idx * 16);
            async_ld16(Bt + (n0 + row) * (long)K + k0 + kk, (char*)Bs + idx * 16);
        }
        __syncthreads();

        bf16x8 af[4], bfr[4];
#pragma unroll
        for (int i = 0; i < 4; i++) {
            af[i]  = *(const bf16x8*)(As + (wm + i * 16 + c) * 32 + g * 8);
            bfr[i] = *(const bf16x8*)(Bs + (wn + i * 16 + c) * 32 + g * 8);
        }
#pragma unroll
        for (int i = 0; i < 4; i++)
#pragma unroll
            for (int j = 0; j < 4; j++)
                acc[i][j] = __builtin_amdgcn_mfma_f32_16x16x32_bf16(af[i], bfr[j], acc[i][j], 0, 0, 0);
    }

    // epilogue: wave-uniform head = (n0+wn)/64; lane c owns d' = 4c..4c+3 (b64 store)
    const int head = (int)((n0 + wn) >> 6);       // 0..35
    const int rm   = wm + g * 4;
    float bv[4];
#pragma unroll
    for (int j = 0; j < 4; j++) bv[j] = bias[(int)n0 + wn + c + 16 * j];
    const int bb    = (int)(m0 >> 10);
    const int sbase = ((int)m0 & 1023) + rm;

    if (head < 24) {
        const float sc = (head < 12) ? 0.125f : 1.0f;
        bf16* dst = ((head < 12) ? qpack : kpack)
                  + (((size_t)((bb * H_ + (head < 12 ? head : head - 12)) * 1024 + sbase)) << 6)
                  + 4 * c;
#pragma unroll
        for (int i = 0; i < 4; i++)
#pragma unroll
            for (int e = 0; e < 4; e++) {
                union { bf16 h4[4]; uint64_t u; } pk;
#pragma unroll
                for (int j = 0; j < 4; j++) pk.h4[j] = (bf16)((acc[i][j][e] + bv[j]) * sc);
                *(uint64_t*)(dst + (size_t)(i * 16 + e) * 64) = pk.u;
            }
    } else {
        bf16* dst = vbuf + ((size_t)(bb * 1024 + sbase)) * 768 + (head - 24) * 64 + 4 * c;
#pragma unroll
        for (int i = 0; i < 4; i++)
#pragma unroll
            for (int e = 0; e < 4; e++) {
                union { bf16 h4[4]; uint64_t u; } pk;
#pragma unroll
                for (int j = 0; j < 4; j++) pk.h4[j] = (bf16)(acc[i][j][e] + bv[j]);
                *(uint64_t*)(dst + (size_t)(i * 16 + e) * 768) = pk.u;
            }
    }
}

// ---------------- generic GEMM (proj): C[M][N] = A[M][K]*Bt[N][K]^T + bias
__global__ __launch_bounds__(256, 2) void gemm_bt(
    const bf16* __restrict__ A, const bf16* __restrict__ Bt,
    const float* __restrict__ bias, float* __restrict__ C,
    int M, int N, int K)
{
    __shared__ __align__(16) bf16 As[128 * 32];
    __shared__ __align__(16) bf16 Bs[128 * 32];

    const int tid  = threadIdx.x;
    const int lane = tid & 63;
    const int w    = tid >> 6;
    const int wm   = (w >> 1) * 64;
    const int wn   = (w & 1) * 64;
    const long m0  = (long)blockIdx.y * 128;
    const long n0  = (long)blockIdx.x * 128;
    const int c    = lane & 15;
    const int g    = lane >> 4;

    const floatx4 fzero = {0.f, 0.f, 0.f, 0.f};
    floatx4 acc[4][4];
#pragma unroll
    for (int i = 0; i < 4; i++)
#pragma unroll
        for (int j = 0; j < 4; j++) acc[i][j] = fzero;

    for (int k0 = 0; k0 < K; k0 += 32) {
        __syncthreads();
#pragma unroll
        for (int r = 0; r < 2; r++) {
            const int idx = r * 256 + tid;
            const int row = idx >> 2;
            const int kk  = (idx & 3) * 8;
            async_ld16(A  + (m0 + row) * (long)K + k0 + kk, (char*)As + idx * 16);
            async_ld16(Bt + (n0 + row) * (long)K + k0 + kk, (char*)Bs + idx * 16);
        }
        __syncthreads();

        bf16x8 af[4], bfr[4];
#pragma unroll
        for (int i = 0; i < 4; i++) {
            af[i]  = *(const bf16x8*)(As + (wm + i * 16 + c) * 32 + g * 8);
            bfr[i] = *(const bf16x8*)(Bs + (wn + i * 16 + c) * 32 + g * 8);
        }
#pragma unroll
        for (int i = 0; i < 4; i++)
#pragma unroll
            for (int j = 0; j < 4; j++)
                acc[i][j] = __builtin_amdgcn_mfma_f32_16x16x32_bf16(af[i], bfr[j], acc[i][j], 0, 0, 0);
    }

    const int cn = wn + c;
    const int rm = wm + g * 4;
#pragma unroll
    for (int j = 0; j < 4; j++) {
        const long gn = n0 + cn + j * 16;
        const float bv = bias[gn];
#pragma unroll
        for (int i = 0; i < 4; i++) {
            const long gm = m0 + rm + i * 16;
#pragma unroll
            for (int e = 0; e < 4; e++)
                C[(gm + e) * (long)N + gn] = acc[i][j][e] + bv;
        }
    }
}

// ---------------- fused attention v5: v3 loop structure (known-good, compiler-scheduled
// __syncthreads staging) with DOUBLED TLP. v4's asm-dbuf regressed (in-loop scratch
// spill: +40MB HBM writes, SGPR 32->112). v3 was grid-limited: 768 blocks = 3 blk/CU
// = 1.5 waves/SIMD, so the per-iter vmcnt(0) drain sat exposed. Now each wave covers
// 32 q instead of 64 (oacc halves -> ~124 regs/thread), grid 1536 = 6 blk/CU =
// 3 waves/SIMD: other blocks' MFMA/exp hides each block's barrier drain. Per-CU MFMA
// work unchanged; staging redundancy x2 comes from L2 (per-XCD K/V set ~3MB < 4MB).
__global__ __launch_bounds__(128, 3) void attn_fused(
    const bf16* __restrict__ qpack, const bf16* __restrict__ kpack,
    const bf16* __restrict__ vt, bf16* __restrict__ outp)
{
    __shared__ __align__(16) bf16 Ks[2048];   // [dc][key][32elem]  (2 planes x 32 keys)
    __shared__ __align__(16) bf16 Vs[2048];   // [d][32key]

    const int tid  = threadIdx.x;
    const int lane = tid & 63;
    const int w    = tid >> 6;
    const int g    = lane >> 4;
    const int c    = lane & 15;

    const int id = blockIdx.x;
    const int bh = id % 96;           // same-(b,h) blocks share id mod 8 -> same XCD
    const int qt = id / 96;           // 0..15
    const int h  = bh >> 3;
    const int b  = bh & 7;
    const int q0 = qt * 64 + w * 32;  // wave covers 32 q rows
    const bf16* qpb = qpack + ((size_t)(b * H_ + h) * 1024) * 64;
    const bf16* kpb = kpack + ((size_t)(b * H_ + h) * 1024) * 64;
    const bf16* vtb = vt    + ((size_t)(b * H_ + h) * 64) * 1024;

    // Q as B-operand: lane holds Q[q = q0+qb*16+c][pos = g*8+j]; loop-invariant
    bf16x8 qf[2][2];
#pragma unroll
    for (int qb = 0; qb < 2; qb++)
#pragma unroll
        for (int dc = 0; dc < 2; dc++)
            qf[qb][dc] = *(const bf16x8*)(qpb + (size_t)(q0 + qb * 16 + c) * 64 + dc * 32 + g * 8);

    union { uint32_t u[4]; bf16x8 v; } onesu;
    onesu.u[0] = onesu.u[1] = onesu.u[2] = onesu.u[3] = 0x3F803F80u;  // bf16 1.0 x8
    const bf16x8 onesf = onesu.v;

    const floatx4 fzero = {0.f, 0.f, 0.f, 0.f};
    floatx4 oacc[2][4];               // [qb][db]: Oᵀ, col=q, row=d (db*16+4g+e)
    floatx4 lacc[2];                  // [qb]: every entry = l[q=c]
#pragma unroll
    for (int qb = 0; qb < 2; qb++) {
        lacc[qb] = fzero;
#pragma unroll
        for (int db = 0; db < 4; db++) oacc[qb][db] = fzero;
    }

    for (int kt = 0; kt < 32; kt++) {       // 32-key groups
        const int kg = kt * 32;
        __syncthreads();
        // stage K tile: 256 chunks of 16B; chunk i: dc=i>>7, key=(i>>2)&31, dch=i&3
#pragma unroll
        for (int r = 0; r < 2; r++) {
            const int i  = r * 128 + tid;
            const int dc = i >> 7, key = (i >> 2) & 31, dch = i & 3;
            async_ld16(kpb + (size_t)(kg + key) * 64 + dc * 32 + dch * 8, (char*)Ks + i * 16);
        }
        // stage V tile: chunk i: d=i>>2, kch=i&3  (vt keys pre-permuted)
#pragma unroll
        for (int r = 0; r < 2; r++) {
            const int i = r * 128 + tid;
            const int d = i >> 2, kch = i & 3;
            async_ld16(vtb + (size_t)d * 1024 + kg + kch * 8, (char*)Vs + i * 16);
        }
        __syncthreads();

        // K as A-operand: lane holds K[key = kb*16+c][pos = dc*32+g*8+j]
        bf16x8 kf[2][2];
#pragma unroll
        for (int kb = 0; kb < 2; kb++)
#pragma unroll
            for (int dc = 0; dc < 2; dc++)
                kf[kb][dc] = *(const bf16x8*)(Ks + (dc * 32 + kb * 16 + c) * 32 + g * 8);

        // Vᵀ as A-operand: lane holds Vᵀ[d = db*16+c][key' = g*8+j]
        bf16x8 vf[4];
#pragma unroll
        for (int db = 0; db < 4; db++)
            vf[db] = *(const bf16x8*)(Vs + (db * 16 + c) * 32 + g * 8);

#pragma unroll
        for (int qb = 0; qb < 2; qb++) {
            // Sᵀ for 32 keys x 16 q
            floatx4 s0 = fzero, s1 = fzero;
#pragma unroll
            for (int dc = 0; dc < 2; dc++) {
                s0 = __builtin_amdgcn_mfma_f32_16x16x32_bf16(kf[0][dc], qf[qb][dc], s0, 0, 0, 0);
                s1 = __builtin_amdgcn_mfma_f32_16x16x32_bf16(kf[1][dc], qf[qb][dc], s1, 0, 0, 0);
            }
            // P = exp(Sᵀ): lane's 8 values are exactly the PV B-operand slots
            union { bf16 e[8]; bf16x8 v; } pa;
#pragma unroll
            for (int e4 = 0; e4 < 4; e4++) {
                pa.e[e4]     = (bf16)__expf(s0[e4]);
                pa.e[e4 + 4] = (bf16)__expf(s1[e4]);
            }
            // Oᵀ += Vᵀ·Pᵀ ; l += 1·Pᵀ
            lacc[qb] = __builtin_amdgcn_mfma_f32_16x16x32_bf16(onesf, pa.v, lacc[qb], 0, 0, 0);
#pragma unroll
            for (int db = 0; db < 4; db++)
                oacc[qb][db] = __builtin_amdgcn_mfma_f32_16x16x32_bf16(vf[db], pa.v, oacc[qb][db], 0, 0, 0);
        }
    }

    // epilogue: lane holds q = q0+qb*16+c, d = db*16+4g+e; pack e-pairs -> b32 stores
#pragma unroll
    for (int qb = 0; qb < 2; qb++) {
        const float linv = 1.0f / lacc[qb][0];
        bf16* orow = outp + ((size_t)b * S_ + q0 + qb * 16 + c) * D_ + h * 64;
#pragma unroll
        for (int db = 0; db < 4; db++)
#pragma unroll
            for (int f = 0; f < 2; f++) {
                union { bf16 hh[2]; uint32_t u; } pk_;
                pk_.hh[0] = (bf16)(oacc[qb][db][2 * f]     * linv);
                pk_.hh[1] = (bf16)(oacc[qb][db][2 * f + 1] * linv);
                *(uint32_t*)(orow + db * 16 + 4 * g + 2 * f) = pk_.u;
            }
    }
}

extern "C" void kernel_launch(void* const* d_in, const int* in_sizes, int n_in,
                              void* d_out, int out_size, void* d_ws, size_t ws_size,
                              hipStream_t stream) {
    const float* x      = (const float*)d_in[0];
    const float* w_qkv  = (const float*)d_in[1];
    const float* b_qkv  = (const float*)d_in[2];
    const float* w_proj = (const float*)d_in[3];
    const float* b_proj = (const float*)d_in[4];
    float* out = (float*)d_out;

    bf16* xb     = (bf16*)d_ws;                       // [8192][768]
    bf16* wqkvt  = xb     + (size_t)8192 * 768;       // [2304][768]
    bf16* wprojt = wqkvt  + (size_t)2304 * 768;       // [768][768]
    bf16* qpack  = wprojt + (size_t)768 * 768;        // [8][12][1024][64] d'-order
    bf16* kpack  = qpack  + (size_t)96 * 1024 * 64;   // [8][12][1024][64] d'-order
    bf16* vbuf   = kpack  + (size_t)96 * 1024 * 64;   // [8192][768] d'-order heads
    bf16* vt     = vbuf   + (size_t)8192 * 768;       // [8][12][64][1024] true-d, perm keys
    bf16* attnb  = xb;                                // alias (xb dead after QKV GEMM)

    prep_all<<<6720, 256, 0, stream>>>(x, w_qkv, w_proj, xb, wqkvt, wprojt);
    gemm_qkv<<<dim3(18, 64), 256, 0, stream>>>(xb, wqkvt, b_qkv, qpack, kpack, vbuf);
    transpose_v<<<dim3(16, 12, 8), 256, 0, stream>>>(vbuf, vt);
    attn_fused<<<1536, 128, 0, stream>>>(qpack, kpack, vt, attnb);
    gemm_bt<<<dim3(6, 64), 256, 0, stream>>>(attnb, wprojt, b_proj, out, 8192, 768, 768);
}

// Round 3
// 195.607 us; speedup vs baseline: 1.1803x; 1.0231x over previous
//
#include <hip/hip_runtime.h>
#include <cstdint>
#include <cmath>

#define B_ 8
#define S_ 1024
#define D_ 768
#define H_ 12
#define HD_ 64

typedef __bf16 bf16;
typedef __attribute__((ext_vector_type(8))) __bf16 bf16x8;
typedef __attribute__((ext_vector_type(4))) float floatx4;

typedef const __attribute__((address_space(1))) unsigned int* gas_ptr;
typedef __attribute__((address_space(3))) unsigned int* las_ptr;

// async global->LDS, 16B per lane. LDS dest must be wave-uniform base + lane*16.
__device__ __forceinline__ void async_ld16(const void* g, void* l) {
    gas_ptr gp = (gas_ptr)(uintptr_t)g;
    las_ptr lp = (las_ptr)(unsigned)(uintptr_t)l;
    __builtin_amdgcn_global_load_lds(gp, lp, 16, 0, 0);
}

// ---------------- tiled transpose-convert body: in[K][N] f32 -> out[N][K] bf16
__device__ __forceinline__ void transpose_dev(const float* __restrict__ in,
                                              bf16* __restrict__ out,
                                              int N, int K, int n0, int k0,
                                              bf16 (*tile)[66], int tid) {
#pragma unroll
    for (int r = 0; r < 4; r++) {
        int idx = r * 256 + tid;
        int row = idx >> 4;
        int c0  = (idx & 15) * 4;
        float4 v = *(const float4*)(in + (size_t)(k0 + row) * N + n0 + c0);
        tile[c0 + 0][row] = (bf16)v.x;
        tile[c0 + 1][row] = (bf16)v.y;
        tile[c0 + 2][row] = (bf16)v.z;
        tile[c0 + 3][row] = (bf16)v.w;
    }
    __syncthreads();
#pragma unroll
    for (int r = 0; r < 2; r++) {
        int idx = r * 256 + tid;
        int orow = idx >> 3;
        int kk   = (idx & 7) * 8;
        union { bf16x8 v; bf16 e[8]; } u;
#pragma unroll
        for (int j = 0; j < 8; j++) u.e[j] = tile[orow][kk + j];
        *(bf16x8*)(out + (size_t)(n0 + orow) * K + k0 + kk) = u.v;
    }
}

// ---------------- fused prep: x f32->bf16 (blocks 0..6143), w_qkv^T (6144..6575),
// w_proj^T (6576..6719)
__global__ __launch_bounds__(256) void prep_all(
    const float* __restrict__ x, const float* __restrict__ w_qkv,
    const float* __restrict__ w_proj,
    bf16* __restrict__ xb, bf16* __restrict__ wqkvt, bf16* __restrict__ wprojt)
{
    __shared__ bf16 tile[64][66];
    const int blk = blockIdx.x, tid = threadIdx.x;
    if (blk < 6144) {
        int i = (blk * 256 + tid) * 4;
        float4 v = *(const float4*)(x + i);
        xb[i]     = (bf16)v.x;
        xb[i + 1] = (bf16)v.y;
        xb[i + 2] = (bf16)v.z;
        xb[i + 3] = (bf16)v.w;
    } else if (blk < 6576) {
        int t = blk - 6144;
        transpose_dev(w_qkv, wqkvt, 2304, 768, (t % 36) * 64, (t / 36) * 64, tile, tid);
    } else {
        int t = blk - 6576;
        transpose_dev(w_proj, wprojt, 768, 768, (t % 12) * 64, (t / 12) * 64, tile, tid);
    }
}

// ---------------- transpose V: vbuf[b][s][768] (head dims in d'-order) -> vt[b][h][d][1024],
// keys PERMUTED for the PV B-operand: within each 32-key group, permuted position kp
// (g=kp>>3, j=kp&7) holds true key  j<4 ? 4g+j : 16+4g+(j-4).
// vbuf memory position p within a head holds true dim dt = (p>>2) + 16*(p&3).
__global__ void transpose_v(const bf16* __restrict__ vbuf, bf16* __restrict__ vt) {
    __shared__ bf16 tile[64][66];     // [true d][key true order]
    const int tid = threadIdx.x;
    const int kt = blockIdx.x, h = blockIdx.y, b = blockIdx.z;
    const bf16* src = vbuf + ((size_t)b * S_ + (size_t)kt * 64) * D_ + h * 64;
#pragma unroll
    for (int r = 0; r < 2; r++) {
        int idx = r * 256 + tid;
        int kr = idx >> 3;
        int d0 = (idx & 7) * 8;
        bf16x8 v = *(const bf16x8*)(src + (size_t)kr * D_ + d0);
#pragma unroll
        for (int j = 0; j < 8; j++) {
            int p  = d0 + j;
            int dt = (p >> 2) + 16 * (p & 3);   // undo d'-permutation
            tile[dt][kr] = v[j];
        }
    }
    __syncthreads();
    bf16* dst = vt + ((size_t)(b * H_ + h) * 64) * 1024 + kt * 64;
#pragma unroll
    for (int r = 0; r < 2; r++) {
        int idx = r * 256 + tid;
        int dr = idx >> 3;
        int k0 = (idx & 7) * 8;
        union { bf16x8 v; bf16 e[8]; } u;
#pragma unroll
        for (int j = 0; j < 8; j++) {
            int kp  = k0 + j;
            int grp = kp & 32;
            int w32 = kp & 31;
            int gg  = w32 >> 3;
            int jj  = w32 & 7;
            int tk  = grp + ((jj < 4) ? (4 * gg + jj) : (16 + 4 * gg + jj - 4));
            u.e[j] = tile[dr][tk];
        }
        *(bf16x8*)(dst + (size_t)dr * 1024 + k0) = u.v;
    }
}

// ---------------- QKV GEMM v2: BK=64 as two independent BK=32 slices staged per
// iteration (ONE vmcnt(0)+barrier drain per 64 K instead of per 32) + 3 blocks/CU.
// R2 counters showed latency-bound: MfmaUtil 20%, iter wall ~2400cyc vs 512cyc of
// MFMA at 2 blk/CU. Doubling MFMA-per-drain + 1.5x waves -> util ~2-3x. Two separate
// [128][32] tiles keep the proven 64B-row-stride ds_read pattern (a [128][64] tile
// would be a 16-way bank conflict, G4).
__global__ __launch_bounds__(256, 3) void gemm_qkv(
    const bf16* __restrict__ A, const bf16* __restrict__ Bt,
    const float* __restrict__ bias,
    bf16* __restrict__ qpack, bf16* __restrict__ kpack, bf16* __restrict__ vbuf)
{
    __shared__ __align__(16) bf16 As[2][128 * 32];
    __shared__ __align__(16) bf16 Bs[2][128 * 32];
    const int N = 2304, K = 768;

    const int tid  = threadIdx.x;
    const int lane = tid & 63;
    const int w    = tid >> 6;
    const int wm   = (w >> 1) * 64;
    const int wn   = (w & 1) * 64;
    const long m0  = (long)blockIdx.y * 128;
    const long n0  = (long)blockIdx.x * 128;
    const int c    = lane & 15;
    const int g    = lane >> 4;

    const floatx4 fzero = {0.f, 0.f, 0.f, 0.f};
    floatx4 acc[4][4];
#pragma unroll
    for (int i = 0; i < 4; i++)
#pragma unroll
        for (int j = 0; j < 4; j++) acc[i][j] = fzero;

    const int row = tid >> 2;          // staging row (0..63 per r-step... 0..127 over 2)
    const int kk  = (tid & 3) * 8;     // staging k-chunk within slice

    for (int k0 = 0; k0 < K; k0 += 64) {
        __syncthreads();
#pragma unroll
        for (int s = 0; s < 2; s++) {
            const int kb = k0 + s * 32;
#pragma unroll
            for (int r = 0; r < 2; r++) {
                const int idx = r * 256 + tid;
                const int rr  = idx >> 2;
                const int kc  = (idx & 3) * 8;
                async_ld16(A  + (m0 + rr) * (long)K + kb + kc, (char*)As[s] + idx * 16);
                async_ld16(Bt + (n0 + rr) * (long)K + kb + kc, (char*)Bs[s] + idx * 16);
            }
        }
        __syncthreads();

#pragma unroll
        for (int s = 0; s < 2; s++) {
            bf16x8 af[4], bfr[4];
#pragma unroll
            for (int i = 0; i < 4; i++) {
                af[i]  = *(const bf16x8*)(As[s] + (wm + i * 16 + c) * 32 + g * 8);
                bfr[i] = *(const bf16x8*)(Bs[s] + (wn + i * 16 + c) * 32 + g * 8);
            }
#pragma unroll
            for (int i = 0; i < 4; i++)
#pragma unroll
                for (int j = 0; j < 4; j++)
                    acc[i][j] = __builtin_amdgcn_mfma_f32_16x16x32_bf16(af[i], bfr[j], acc[i][j], 0, 0, 0);
        }
    }

    // epilogue: wave-uniform head = (n0+wn)/64; lane c owns d' = 4c..4c+3 (b64 store)
    const int head = (int)((n0 + wn) >> 6);       // 0..35
    const int rm   = wm + g * 4;
    float bv[4];
#pragma unroll
    for (int j = 0; j < 4; j++) bv[j] = bias[(int)n0 + wn + c + 16 * j];
    const int bb    = (int)(m0 >> 10);
    const int sbase = ((int)m0 & 1023) + rm;

    if (head < 24) {
        const float sc = (head < 12) ? 0.125f : 1.0f;
        bf16* dst = ((head < 12) ? qpack : kpack)
                  + (((size_t)((bb * H_ + (head < 12 ? head : head - 12)) * 1024 + sbase)) << 6)
                  + 4 * c;
#pragma unroll
        for (int i = 0; i < 4; i++)
#pragma unroll
            for (int e = 0; e < 4; e++) {
                union { bf16 h4[4]; uint64_t u; } pk;
#pragma unroll
                for (int j = 0; j < 4; j++) pk.h4[j] = (bf16)((acc[i][j][e] + bv[j]) * sc);
                *(uint64_t*)(dst + (size_t)(i * 16 + e) * 64) = pk.u;
            }
    } else {
        bf16* dst = vbuf + ((size_t)(bb * 1024 + sbase)) * 768 + (head - 24) * 64 + 4 * c;
#pragma unroll
        for (int i = 0; i < 4; i++)
#pragma unroll
            for (int e = 0; e < 4; e++) {
                union { bf16 h4[4]; uint64_t u; } pk;
#pragma unroll
                for (int j = 0; j < 4; j++) pk.h4[j] = (bf16)(acc[i][j][e] + bv[j]);
                *(uint64_t*)(dst + (size_t)(i * 16 + e) * 768) = pk.u;
            }
    }
}

// ---------------- generic GEMM (proj) v2: same BK=64 two-slice structure.
__global__ __launch_bounds__(256, 3) void gemm_bt(
    const bf16* __restrict__ A, const bf16* __restrict__ Bt,
    const float* __restrict__ bias, float* __restrict__ C,
    int M, int N, int K)
{
    __shared__ __align__(16) bf16 As[2][128 * 32];
    __shared__ __align__(16) bf16 Bs[2][128 * 32];

    const int tid  = threadIdx.x;
    const int lane = tid & 63;
    const int w    = tid >> 6;
    const int wm   = (w >> 1) * 64;
    const int wn   = (w & 1) * 64;
    const long m0  = (long)blockIdx.y * 128;
    const long n0  = (long)blockIdx.x * 128;
    const int c    = lane & 15;
    const int g    = lane >> 4;

    const floatx4 fzero = {0.f, 0.f, 0.f, 0.f};
    floatx4 acc[4][4];
#pragma unroll
    for (int i = 0; i < 4; i++)
#pragma unroll
        for (int j = 0; j < 4; j++) acc[i][j] = fzero;

    for (int k0 = 0; k0 < K; k0 += 64) {
        __syncthreads();
#pragma unroll
        for (int s = 0; s < 2; s++) {
            const int kb = k0 + s * 32;
#pragma unroll
            for (int r = 0; r < 2; r++) {
                const int idx = r * 256 + tid;
                const int rr  = idx >> 2;
                const int kc  = (idx & 3) * 8;
                async_ld16(A  + (m0 + rr) * (long)K + kb + kc, (char*)As[s] + idx * 16);
                async_ld16(Bt + (n0 + rr) * (long)K + kb + kc, (char*)Bs[s] + idx * 16);
            }
        }
        __syncthreads();

#pragma unroll
        for (int s = 0; s < 2; s++) {
            bf16x8 af[4], bfr[4];
#pragma unroll
            for (int i = 0; i < 4; i++) {
                af[i]  = *(const bf16x8*)(As[s] + (wm + i * 16 + c) * 32 + g * 8);
                bfr[i] = *(const bf16x8*)(Bs[s] + (wn + i * 16 + c) * 32 + g * 8);
            }
#pragma unroll
            for (int i = 0; i < 4; i++)
#pragma unroll
                for (int j = 0; j < 4; j++)
                    acc[i][j] = __builtin_amdgcn_mfma_f32_16x16x32_bf16(af[i], bfr[j], acc[i][j], 0, 0, 0);
        }
    }

    const int cn = wn + c;
    const int rm = wm + g * 4;
#pragma unroll
    for (int j = 0; j < 4; j++) {
        const long gn = n0 + cn + j * 16;
        const float bv = bias[gn];
#pragma unroll
        for (int i = 0; i < 4; i++) {
            const long gm = m0 + rm + i * 16;
#pragma unroll
            for (int e = 0; e < 4; e++)
                C[(gm + e) * (long)N + gn] = acc[i][j][e] + bv;
        }
    }
}

// ---------------- fused attention v5 (unchanged from R2: known-good, 1536 blocks =
// 6 blk/CU = 3 waves/SIMD; TLP hides the per-iter staging drain).
__global__ __launch_bounds__(128, 3) void attn_fused(
    const bf16* __restrict__ qpack, const bf16* __restrict__ kpack,
    const bf16* __restrict__ vt, bf16* __restrict__ outp)
{
    __shared__ __align__(16) bf16 Ks[2048];   // [dc][key][32elem]  (2 planes x 32 keys)
    __shared__ __align__(16) bf16 Vs[2048];   // [d][32key]

    const int tid  = threadIdx.x;
    const int lane = tid & 63;
    const int w    = tid >> 6;
    const int g    = lane >> 4;
    const int c    = lane & 15;

    const int id = blockIdx.x;
    const int bh = id % 96;           // same-(b,h) blocks share id mod 8 -> same XCD
    const int qt = id / 96;           // 0..15
    const int h  = bh >> 3;
    const int b  = bh & 7;
    const int q0 = qt * 64 + w * 32;  // wave covers 32 q rows
    const bf16* qpb = qpack + ((size_t)(b * H_ + h) * 1024) * 64;
    const bf16* kpb = kpack + ((size_t)(b * H_ + h) * 1024) * 64;
    const bf16* vtb = vt    + ((size_t)(b * H_ + h) * 64) * 1024;

    // Q as B-operand: lane holds Q[q = q0+qb*16+c][pos = g*8+j]; loop-invariant
    bf16x8 qf[2][2];
#pragma unroll
    for (int qb = 0; qb < 2; qb++)
#pragma unroll
        for (int dc = 0; dc < 2; dc++)
            qf[qb][dc] = *(const bf16x8*)(qpb + (size_t)(q0 + qb * 16 + c) * 64 + dc * 32 + g * 8);

    union { uint32_t u[4]; bf16x8 v; } onesu;
    onesu.u[0] = onesu.u[1] = onesu.u[2] = onesu.u[3] = 0x3F803F80u;  // bf16 1.0 x8
    const bf16x8 onesf = onesu.v;

    const floatx4 fzero = {0.f, 0.f, 0.f, 0.f};
    floatx4 oacc[2][4];               // [qb][db]: Oᵀ, col=q, row=d (db*16+4g+e)
    floatx4 lacc[2];                  // [qb]: every entry = l[q=c]
#pragma unroll
    for (int qb = 0; qb < 2; qb++) {
        lacc[qb] = fzero;
#pragma unroll
        for (int db = 0; db < 4; db++) oacc[qb][db] = fzero;
    }

    for (int kt = 0; kt < 32; kt++) {       // 32-key groups
        const int kg = kt * 32;
        __syncthreads();
        // stage K tile: 256 chunks of 16B; chunk i: dc=i>>7, key=(i>>2)&31, dch=i&3
#pragma unroll
        for (int r = 0; r < 2; r++) {
            const int i  = r * 128 + tid;
            const int dc = i >> 7, key = (i >> 2) & 31, dch = i & 3;
            async_ld16(kpb + (size_t)(kg + key) * 64 + dc * 32 + dch * 8, (char*)Ks + i * 16);
        }
        // stage V tile: chunk i: d=i>>2, kch=i&3  (vt keys pre-permuted)
#pragma unroll
        for (int r = 0; r < 2; r++) {
            const int i = r * 128 + tid;
            const int d = i >> 2, kch = i & 3;
            async_ld16(vtb + (size_t)d * 1024 + kg + kch * 8, (char*)Vs + i * 16);
        }
        __syncthreads();

        // K as A-operand: lane holds K[key = kb*16+c][pos = dc*32+g*8+j]
        bf16x8 kf[2][2];
#pragma unroll
        for (int kb = 0; kb < 2; kb++)
#pragma unroll
            for (int dc = 0; dc < 2; dc++)
                kf[kb][dc] = *(const bf16x8*)(Ks + (dc * 32 + kb * 16 + c) * 32 + g * 8);

        // Vᵀ as A-operand: lane holds Vᵀ[d = db*16+c][key' = g*8+j]
        bf16x8 vf[4];
#pragma unroll
        for (int db = 0; db < 4; db++)
            vf[db] = *(const bf16x8*)(Vs + (db * 16 + c) * 32 + g * 8);

#pragma unroll
        for (int qb = 0; qb < 2; qb++) {
            // Sᵀ for 32 keys x 16 q
            floatx4 s0 = fzero, s1 = fzero;
#pragma unroll
            for (int dc = 0; dc < 2; dc++) {
                s0 = __builtin_amdgcn_mfma_f32_16x16x32_bf16(kf[0][dc], qf[qb][dc], s0, 0, 0, 0);
                s1 = __builtin_amdgcn_mfma_f32_16x16x32_bf16(kf[1][dc], qf[qb][dc], s1, 0, 0, 0);
            }
            // P = exp(Sᵀ): lane's 8 values are exactly the PV B-operand slots
            union { bf16 e[8]; bf16x8 v; } pa;
#pragma unroll
            for (int e4 = 0; e4 < 4; e4++) {
                pa.e[e4]     = (bf16)__expf(s0[e4]);
                pa.e[e4 + 4] = (bf16)__expf(s1[e4]);
            }
            // Oᵀ += Vᵀ·Pᵀ ; l += 1·Pᵀ
            lacc[qb] = __builtin_amdgcn_mfma_f32_16x16x32_bf16(onesf, pa.v, lacc[qb], 0, 0, 0);
#pragma unroll
            for (int db = 0; db < 4; db++)
                oacc[qb][db] = __builtin_amdgcn_mfma_f32_16x16x32_bf16(vf[db], pa.v, oacc[qb][db], 0, 0, 0);
        }
    }

    // epilogue: lane holds q = q0+qb*16+c, d = db*16+4g+e; pack e-pairs -> b32 stores
#pragma unroll
    for (int qb = 0; qb < 2; qb++) {
        const float linv = 1.0f / lacc[qb][0];
        bf16* orow = outp + ((size_t)b * S_ + q0 + qb * 16 + c) * D_ + h * 64;
#pragma unroll
        for (int db = 0; db < 4; db++)
#pragma unroll
            for (int f = 0; f < 2; f++) {
                union { bf16 hh[2]; uint32_t u; } pk_;
                pk_.hh[0] = (bf16)(oacc[qb][db][2 * f]     * linv);
                pk_.hh[1] = (bf16)(oacc[qb][db][2 * f + 1] * linv);
                *(uint32_t*)(orow + db * 16 + 4 * g + 2 * f) = pk_.u;
            }
    }
}

extern "C" void kernel_launch(void* const* d_in, const int* in_sizes, int n_in,
                              void* d_out, int out_size, void* d_ws, size_t ws_size,
                              hipStream_t stream) {
    const float* x      = (const float*)d_in[0];
    const float* w_qkv  = (const float*)d_in[1];
    const float* b_qkv  = (const float*)d_in[2];
    const float* w_proj = (const float*)d_in[3];
    const float* b_proj = (const float*)d_in[4];
    float* out = (float*)d_out;

    bf16* xb     = (bf16*)d_ws;                       // [8192][768]
    bf16* wqkvt  = xb     + (size_t)8192 * 768;       // [2304][768]
    bf16* wprojt = wqkvt  + (size_t)2304 * 768;       // [768][768]
    bf16* qpack  = wprojt + (size_t)768 * 768;        // [8][12][1024][64] d'-order
    bf16* kpack  = qpack  + (size_t)96 * 1024 * 64;   // [8][12][1024][64] d'-order
    bf16* vbuf   = kpack  + (size_t)96 * 1024 * 64;   // [8192][768] d'-order heads
    bf16* vt     = vbuf   + (size_t)8192 * 768;       // [8][12][64][1024] true-d, perm keys
    bf16* attnb  = xb;                                // alias (xb dead after QKV GEMM)

    prep_all<<<6720, 256, 0, stream>>>(x, w_qkv, w_proj, xb, wqkvt, wprojt);
    gemm_qkv<<<dim3(18, 64), 256, 0, stream>>>(xb, wqkvt, b_qkv, qpack, kpack, vbuf);
    transpose_v<<<dim3(16, 12, 8), 256, 0, stream>>>(vbuf, vt);
    attn_fused<<<1536, 128, 0, stream>>>(qpack, kpack, vt, attnb);
    gemm_bt<<<dim3(6, 64), 256, 0, stream>>>(attnb, wprojt, b_proj, out, 8192, 768, 768);
}

// Round 4
// 189.332 us; speedup vs baseline: 1.2194x; 1.0331x over previous
//
#include <hip/hip_runtime.h>
#include <cstdint>
#include <cmath>

#define B_ 8
#define S_ 1024
#define D_ 768
#define H_ 12
#define HD_ 64

typedef __bf16 bf16;
typedef __attribute__((ext_vector_type(8))) __bf16 bf16x8;
typedef __attribute__((ext_vector_type(4))) float floatx4;

typedef const __attribute__((address_space(1))) unsigned int* gas_ptr;
typedef __attribute__((address_space(3))) unsigned int* las_ptr;

// async global->LDS, 16B per lane. LDS dest must be wave-uniform base + lane*16.
__device__ __forceinline__ void async_ld16(const void* g, void* l) {
    gas_ptr gp = (gas_ptr)(uintptr_t)g;
    las_ptr lp = (las_ptr)(unsigned)(uintptr_t)l;
    __builtin_amdgcn_global_load_lds(gp, lp, 16, 0, 0);
}

// XCD-chunked swizzle (T1): physical XCD = linear_wgid % 8. Give each XCD a
// contiguous m-chunk (ny/8 rows x all nx cols) so A-panels are HBM-missed once
// per chip, then L2-hit. Requires ny % 8 == 0 (bijective). Returns (bx, by).
__device__ __forceinline__ void xcd_swizzle(int& bx, int& by) {
    const int nx = gridDim.x, ny = gridDim.y;
    const int lin = blockIdx.y * nx + blockIdx.x;
    const int xcd = lin & 7;
    const int loc = lin >> 3;
    by = xcd * (ny >> 3) + loc / nx;
    bx = loc % nx;
}

// ---------------- tiled transpose-convert body: in[K][N] f32 -> out[N][K] bf16
__device__ __forceinline__ void transpose_dev(const float* __restrict__ in,
                                              bf16* __restrict__ out,
                                              int N, int K, int n0, int k0,
                                              bf16 (*tile)[66], int tid) {
#pragma unroll
    for (int r = 0; r < 4; r++) {
        int idx = r * 256 + tid;
        int row = idx >> 4;
        int c0  = (idx & 15) * 4;
        float4 v = *(const float4*)(in + (size_t)(k0 + row) * N + n0 + c0);
        tile[c0 + 0][row] = (bf16)v.x;
        tile[c0 + 1][row] = (bf16)v.y;
        tile[c0 + 2][row] = (bf16)v.z;
        tile[c0 + 3][row] = (bf16)v.w;
    }
    __syncthreads();
#pragma unroll
    for (int r = 0; r < 2; r++) {
        int idx = r * 256 + tid;
        int orow = idx >> 3;
        int kk   = (idx & 7) * 8;
        union { bf16x8 v; bf16 e[8]; } u;
#pragma unroll
        for (int j = 0; j < 8; j++) u.e[j] = tile[orow][kk + j];
        *(bf16x8*)(out + (size_t)(n0 + orow) * K + k0 + kk) = u.v;
    }
}

// ---------------- fused prep: x f32->bf16 (blocks 0..6143), w_qkv^T (6144..6575),
// w_proj^T (6576..6719)
__global__ __launch_bounds__(256) void prep_all(
    const float* __restrict__ x, const float* __restrict__ w_qkv,
    const float* __restrict__ w_proj,
    bf16* __restrict__ xb, bf16* __restrict__ wqkvt, bf16* __restrict__ wprojt)
{
    __shared__ bf16 tile[64][66];
    const int blk = blockIdx.x, tid = threadIdx.x;
    if (blk < 6144) {
        int i = (blk * 256 + tid) * 4;
        float4 v = *(const float4*)(x + i);
        xb[i]     = (bf16)v.x;
        xb[i + 1] = (bf16)v.y;
        xb[i + 2] = (bf16)v.z;
        xb[i + 3] = (bf16)v.w;
    } else if (blk < 6576) {
        int t = blk - 6144;
        transpose_dev(w_qkv, wqkvt, 2304, 768, (t % 36) * 64, (t / 36) * 64, tile, tid);
    } else {
        int t = blk - 6576;
        transpose_dev(w_proj, wprojt, 768, 768, (t % 12) * 64, (t / 12) * 64, tile, tid);
    }
}

// ---------------- transpose V: vbuf[b][s][768] (head dims in d'-order) -> vt[b][h][d][1024],
// keys PERMUTED for the PV B-operand: within each 32-key group, permuted position kp
// (g=kp>>3, j=kp&7) holds true key  j<4 ? 4g+j : 16+4g+(j-4).
// vbuf memory position p within a head holds true dim dt = (p>>2) + 16*(p&3).
__global__ void transpose_v(const bf16* __restrict__ vbuf, bf16* __restrict__ vt) {
    __shared__ bf16 tile[64][66];     // [true d][key true order]
    const int tid = threadIdx.x;
    const int kt = blockIdx.x, h = blockIdx.y, b = blockIdx.z;
    const bf16* src = vbuf + ((size_t)b * S_ + (size_t)kt * 64) * D_ + h * 64;
#pragma unroll
    for (int r = 0; r < 2; r++) {
        int idx = r * 256 + tid;
        int kr = idx >> 3;
        int d0 = (idx & 7) * 8;
        bf16x8 v = *(const bf16x8*)(src + (size_t)kr * D_ + d0);
#pragma unroll
        for (int j = 0; j < 8; j++) {
            int p  = d0 + j;
            int dt = (p >> 2) + 16 * (p & 3);   // undo d'-permutation
            tile[dt][kr] = v[j];
        }
    }
    __syncthreads();
    bf16* dst = vt + ((size_t)(b * H_ + h) * 64) * 1024 + kt * 64;
#pragma unroll
    for (int r = 0; r < 2; r++) {
        int idx = r * 256 + tid;
        int dr = idx >> 3;
        int k0 = (idx & 7) * 8;
        union { bf16x8 v; bf16 e[8]; } u;
#pragma unroll
        for (int j = 0; j < 8; j++) {
            int kp  = k0 + j;
            int grp = kp & 32;
            int w32 = kp & 31;
            int gg  = w32 >> 3;
            int jj  = w32 & 7;
            int tk  = grp + ((jj < 4) ? (4 * gg + jj) : (16 + 4 * gg + jj - 4));
            u.e[j] = tile[dr][tk];
        }
        *(bf16x8*)(dst + (size_t)dr * 1024 + k0) = u.v;
    }
}

// ---------------- QKV GEMM v3: BK=64 two-slice (R3) + XCD-chunked swizzle (R4).
// R3 counters: MfmaUtil 22%, FETCH 67.5MB vs ideal 16MB -> A-panels HBM-missed ~5x
// because the 18 blocks sharing a panel were round-robined over 8 XCDs. Chunking
// m-rows per XCD makes A 1-miss-then-L2-hit; staging drain latency ~halves.
__global__ __launch_bounds__(256, 3) void gemm_qkv(
    const bf16* __restrict__ A, const bf16* __restrict__ Bt,
    const float* __restrict__ bias,
    bf16* __restrict__ qpack, bf16* __restrict__ kpack, bf16* __restrict__ vbuf)
{
    __shared__ __align__(16) bf16 As[2][128 * 32];
    __shared__ __align__(16) bf16 Bs[2][128 * 32];
    const int N = 2304, K = 768;

    const int tid  = threadIdx.x;
    const int lane = tid & 63;
    const int w    = tid >> 6;
    const int wm   = (w >> 1) * 64;
    const int wn   = (w & 1) * 64;
    int bx, by;
    xcd_swizzle(bx, by);
    const long m0  = (long)by * 128;
    const long n0  = (long)bx * 128;
    const int c    = lane & 15;
    const int g    = lane >> 4;

    const floatx4 fzero = {0.f, 0.f, 0.f, 0.f};
    floatx4 acc[4][4];
#pragma unroll
    for (int i = 0; i < 4; i++)
#pragma unroll
        for (int j = 0; j < 4; j++) acc[i][j] = fzero;

    for (int k0 = 0; k0 < K; k0 += 64) {
        __syncthreads();
#pragma unroll
        for (int s = 0; s < 2; s++) {
            const int kb = k0 + s * 32;
#pragma unroll
            for (int r = 0; r < 2; r++) {
                const int idx = r * 256 + tid;
                const int rr  = idx >> 2;
                const int kc  = (idx & 3) * 8;
                async_ld16(A  + (m0 + rr) * (long)K + kb + kc, (char*)As[s] + idx * 16);
                async_ld16(Bt + (n0 + rr) * (long)K + kb + kc, (char*)Bs[s] + idx * 16);
            }
        }
        __syncthreads();

#pragma unroll
        for (int s = 0; s < 2; s++) {
            bf16x8 af[4], bfr[4];
#pragma unroll
            for (int i = 0; i < 4; i++) {
                af[i]  = *(const bf16x8*)(As[s] + (wm + i * 16 + c) * 32 + g * 8);
                bfr[i] = *(const bf16x8*)(Bs[s] + (wn + i * 16 + c) * 32 + g * 8);
            }
#pragma unroll
            for (int i = 0; i < 4; i++)
#pragma unroll
                for (int j = 0; j < 4; j++)
                    acc[i][j] = __builtin_amdgcn_mfma_f32_16x16x32_bf16(af[i], bfr[j], acc[i][j], 0, 0, 0);
        }
    }

    // epilogue: wave-uniform head = (n0+wn)/64; lane c owns d' = 4c..4c+3 (b64 store)
    const int head = (int)((n0 + wn) >> 6);       // 0..35
    const int rm   = wm + g * 4;
    float bv[4];
#pragma unroll
    for (int j = 0; j < 4; j++) bv[j] = bias[(int)n0 + wn + c + 16 * j];
    const int bb    = (int)(m0 >> 10);
    const int sbase = ((int)m0 & 1023) + rm;

    if (head < 24) {
        const float sc = (head < 12) ? 0.125f : 1.0f;
        bf16* dst = ((head < 12) ? qpack : kpack)
                  + (((size_t)((bb * H_ + (head < 12 ? head : head - 12)) * 1024 + sbase)) << 6)
                  + 4 * c;
#pragma unroll
        for (int i = 0; i < 4; i++)
#pragma unroll
            for (int e = 0; e < 4; e++) {
                union { bf16 h4[4]; uint64_t u; } pk;
#pragma unroll
                for (int j = 0; j < 4; j++) pk.h4[j] = (bf16)((acc[i][j][e] + bv[j]) * sc);
                *(uint64_t*)(dst + (size_t)(i * 16 + e) * 64) = pk.u;
            }
    } else {
        bf16* dst = vbuf + ((size_t)(bb * 1024 + sbase)) * 768 + (head - 24) * 64 + 4 * c;
#pragma unroll
        for (int i = 0; i < 4; i++)
#pragma unroll
            for (int e = 0; e < 4; e++) {
                union { bf16 h4[4]; uint64_t u; } pk;
#pragma unroll
                for (int j = 0; j < 4; j++) pk.h4[j] = (bf16)(acc[i][j][e] + bv[j]);
                *(uint64_t*)(dst + (size_t)(i * 16 + e) * 768) = pk.u;
            }
    }
}

// ---------------- generic GEMM (proj) v3: BK=64 two-slice + XCD-chunked swizzle.
// Requires gridDim.y % 8 == 0.
__global__ __launch_bounds__(256, 3) void gemm_bt(
    const bf16* __restrict__ A, const bf16* __restrict__ Bt,
    const float* __restrict__ bias, float* __restrict__ C,
    int M, int N, int K)
{
    __shared__ __align__(16) bf16 As[2][128 * 32];
    __shared__ __align__(16) bf16 Bs[2][128 * 32];

    const int tid  = threadIdx.x;
    const int lane = tid & 63;
    const int w    = tid >> 6;
    const int wm   = (w >> 1) * 64;
    const int wn   = (w & 1) * 64;
    int bx, by;
    xcd_swizzle(bx, by);
    const long m0  = (long)by * 128;
    const long n0  = (long)bx * 128;
    const int c    = lane & 15;
    const int g    = lane >> 4;

    const floatx4 fzero = {0.f, 0.f, 0.f, 0.f};
    floatx4 acc[4][4];
#pragma unroll
    for (int i = 0; i < 4; i++)
#pragma unroll
        for (int j = 0; j < 4; j++) acc[i][j] = fzero;

    for (int k0 = 0; k0 < K; k0 += 64) {
        __syncthreads();
#pragma unroll
        for (int s = 0; s < 2; s++) {
            const int kb = k0 + s * 32;
#pragma unroll
            for (int r = 0; r < 2; r++) {
                const int idx = r * 256 + tid;
                const int rr  = idx >> 2;
                const int kc  = (idx & 3) * 8;
                async_ld16(A  + (m0 + rr) * (long)K + kb + kc, (char*)As[s] + idx * 16);
                async_ld16(Bt + (n0 + rr) * (long)K + kb + kc, (char*)Bs[s] + idx * 16);
            }
        }
        __syncthreads();

#pragma unroll
        for (int s = 0; s < 2; s++) {
            bf16x8 af[4], bfr[4];
#pragma unroll
            for (int i = 0; i < 4; i++) {
                af[i]  = *(const bf16x8*)(As[s] + (wm + i * 16 + c) * 32 + g * 8);
                bfr[i] = *(const bf16x8*)(Bs[s] + (wn + i * 16 + c) * 32 + g * 8);
            }
#pragma unroll
            for (int i = 0; i < 4; i++)
#pragma unroll
                for (int j = 0; j < 4; j++)
                    acc[i][j] = __builtin_amdgcn_mfma_f32_16x16x32_bf16(af[i], bfr[j], acc[i][j], 0, 0, 0);
        }
    }

    const int cn = wn + c;
    const int rm = wm + g * 4;
#pragma unroll
    for (int j = 0; j < 4; j++) {
        const long gn = n0 + cn + j * 16;
        const float bv = bias[gn];
#pragma unroll
        for (int i = 0; i < 4; i++) {
            const long gm = m0 + rm + i * 16;
#pragma unroll
            for (int e = 0; e < 4; e++)
                C[(gm + e) * (long)N + gn] = acc[i][j][e] + bv;
        }
    }
}

// ---------------- fused attention v5 (unchanged from R2: known-good, 1536 blocks =
// 6 blk/CU = 3 waves/SIMD; TLP hides the per-iter staging drain).
__global__ __launch_bounds__(128, 3) void attn_fused(
    const bf16* __restrict__ qpack, const bf16* __restrict__ kpack,
    const bf16* __restrict__ vt, bf16* __restrict__ outp)
{
    __shared__ __align__(16) bf16 Ks[2048];   // [dc][key][32elem]  (2 planes x 32 keys)
    __shared__ __align__(16) bf16 Vs[2048];   // [d][32key]

    const int tid  = threadIdx.x;
    const int lane = tid & 63;
    const int w    = tid >> 6;
    const int g    = lane >> 4;
    const int c    = lane & 15;

    const int id = blockIdx.x;
    const int bh = id % 96;           // same-(b,h) blocks share id mod 8 -> same XCD
    const int qt = id / 96;           // 0..15
    const int h  = bh >> 3;
    const int b  = bh & 7;
    const int q0 = qt * 64 + w * 32;  // wave covers 32 q rows
    const bf16* qpb = qpack + ((size_t)(b * H_ + h) * 1024) * 64;
    const bf16* kpb = kpack + ((size_t)(b * H_ + h) * 1024) * 64;
    const bf16* vtb = vt    + ((size_t)(b * H_ + h) * 64) * 1024;

    // Q as B-operand: lane holds Q[q = q0+qb*16+c][pos = g*8+j]; loop-invariant
    bf16x8 qf[2][2];
#pragma unroll
    for (int qb = 0; qb < 2; qb++)
#pragma unroll
        for (int dc = 0; dc < 2; dc++)
            qf[qb][dc] = *(const bf16x8*)(qpb + (size_t)(q0 + qb * 16 + c) * 64 + dc * 32 + g * 8);

    union { uint32_t u[4]; bf16x8 v; } onesu;
    onesu.u[0] = onesu.u[1] = onesu.u[2] = onesu.u[3] = 0x3F803F80u;  // bf16 1.0 x8
    const bf16x8 onesf = onesu.v;

    const floatx4 fzero = {0.f, 0.f, 0.f, 0.f};
    floatx4 oacc[2][4];               // [qb][db]: Oᵀ, col=q, row=d (db*16+4g+e)
    floatx4 lacc[2];                  // [qb]: every entry = l[q=c]
#pragma unroll
    for (int qb = 0; qb < 2; qb++) {
        lacc[qb] = fzero;
#pragma unroll
        for (int db = 0; db < 4; db++) oacc[qb][db] = fzero;
    }

    for (int kt = 0; kt < 32; kt++) {       // 32-key groups
        const int kg = kt * 32;
        __syncthreads();
        // stage K tile: 256 chunks of 16B; chunk i: dc=i>>7, key=(i>>2)&31, dch=i&3
#pragma unroll
        for (int r = 0; r < 2; r++) {
            const int i  = r * 128 + tid;
            const int dc = i >> 7, key = (i >> 2) & 31, dch = i & 3;
            async_ld16(kpb + (size_t)(kg + key) * 64 + dc * 32 + dch * 8, (char*)Ks + i * 16);
        }
        // stage V tile: chunk i: d=i>>2, kch=i&3  (vt keys pre-permuted)
#pragma unroll
        for (int r = 0; r < 2; r++) {
            const int i = r * 128 + tid;
            const int d = i >> 2, kch = i & 3;
            async_ld16(vtb + (size_t)d * 1024 + kg + kch * 8, (char*)Vs + i * 16);
        }
        __syncthreads();

        // K as A-operand: lane holds K[key = kb*16+c][pos = dc*32+g*8+j]
        bf16x8 kf[2][2];
#pragma unroll
        for (int kb = 0; kb < 2; kb++)
#pragma unroll
            for (int dc = 0; dc < 2; dc++)
                kf[kb][dc] = *(const bf16x8*)(Ks + (dc * 32 + kb * 16 + c) * 32 + g * 8);

        // Vᵀ as A-operand: lane holds Vᵀ[d = db*16+c][key' = g*8+j]
        bf16x8 vf[4];
#pragma unroll
        for (int db = 0; db < 4; db++)
            vf[db] = *(const bf16x8*)(Vs + (db * 16 + c) * 32 + g * 8);

#pragma unroll
        for (int qb = 0; qb < 2; qb++) {
            // Sᵀ for 32 keys x 16 q
            floatx4 s0 = fzero, s1 = fzero;
#pragma unroll
            for (int dc = 0; dc < 2; dc++) {
                s0 = __builtin_amdgcn_mfma_f32_16x16x32_bf16(kf[0][dc], qf[qb][dc], s0, 0, 0, 0);
                s1 = __builtin_amdgcn_mfma_f32_16x16x32_bf16(kf[1][dc], qf[qb][dc], s1, 0, 0, 0);
            }
            // P = exp(Sᵀ): lane's 8 values are exactly the PV B-operand slots
            union { bf16 e[8]; bf16x8 v; } pa;
#pragma unroll
            for (int e4 = 0; e4 < 4; e4++) {
                pa.e[e4]     = (bf16)__expf(s0[e4]);
                pa.e[e4 + 4] = (bf16)__expf(s1[e4]);
            }
            // Oᵀ += Vᵀ·Pᵀ ; l += 1·Pᵀ
            lacc[qb] = __builtin_amdgcn_mfma_f32_16x16x32_bf16(onesf, pa.v, lacc[qb], 0, 0, 0);
#pragma unroll
            for (int db = 0; db < 4; db++)
                oacc[qb][db] = __builtin_amdgcn_mfma_f32_16x16x32_bf16(vf[db], pa.v, oacc[qb][db], 0, 0, 0);
        }
    }

    // epilogue: lane holds q = q0+qb*16+c, d = db*16+4g+e; pack e-pairs -> b32 stores
#pragma unroll
    for (int qb = 0; qb < 2; qb++) {
        const float linv = 1.0f / lacc[qb][0];
        bf16* orow = outp + ((size_t)b * S_ + q0 + qb * 16 + c) * D_ + h * 64;
#pragma unroll
        for (int db = 0; db < 4; db++)
#pragma unroll
            for (int f = 0; f < 2; f++) {
                union { bf16 hh[2]; uint32_t u; } pk_;
                pk_.hh[0] = (bf16)(oacc[qb][db][2 * f]     * linv);
                pk_.hh[1] = (bf16)(oacc[qb][db][2 * f + 1] * linv);
                *(uint32_t*)(orow + db * 16 + 4 * g + 2 * f) = pk_.u;
            }
    }
}

extern "C" void kernel_launch(void* const* d_in, const int* in_sizes, int n_in,
                              void* d_out, int out_size, void* d_ws, size_t ws_size,
                              hipStream_t stream) {
    const float* x      = (const float*)d_in[0];
    const float* w_qkv  = (const float*)d_in[1];
    const float* b_qkv  = (const float*)d_in[2];
    const float* w_proj = (const float*)d_in[3];
    const float* b_proj = (const float*)d_in[4];
    float* out = (float*)d_out;

    bf16* xb     = (bf16*)d_ws;                       // [8192][768]
    bf16* wqkvt  = xb     + (size_t)8192 * 768;       // [2304][768]
    bf16* wprojt = wqkvt  + (size_t)2304 * 768;       // [768][768]
    bf16* qpack  = wprojt + (size_t)768 * 768;        // [8][12][1024][64] d'-order
    bf16* kpack  = qpack  + (size_t)96 * 1024 * 64;   // [8][12][1024][64] d'-order
    bf16* vbuf   = kpack  + (size_t)96 * 1024 * 64;   // [8192][768] d'-order heads
    bf16* vt     = vbuf   + (size_t)8192 * 768;       // [8][12][64][1024] true-d, perm keys
    bf16* attnb  = xb;                                // alias (xb dead after QKV GEMM)

    prep_all<<<6720, 256, 0, stream>>>(x, w_qkv, w_proj, xb, wqkvt, wprojt);
    gemm_qkv<<<dim3(18, 64), 256, 0, stream>>>(xb, wqkvt, b_qkv, qpack, kpack, vbuf);
    transpose_v<<<dim3(16, 12, 8), 256, 0, stream>>>(vbuf, vt);
    attn_fused<<<1536, 128, 0, stream>>>(qpack, kpack, vt, attnb);
    gemm_bt<<<dim3(6, 64), 256, 0, stream>>>(attnb, wprojt, b_proj, out, 8192, 768, 768);
}